// Round 1
// baseline (1844.851 us; speedup 1.0000x reference)
//
#include <hip/hip_runtime.h>
#include <math.h>

// HieraFormer fused block: QKV proj -> entmax1.5 attention -> PV -> LN+residual
// B=2, D_MODEL=384, H=3, D_K=128, N=2048. All fp32 this round (correctness first).
#define DM   384
#define NH   3
#define DK   128
#define NSEQ 2048
#define BATCH 2
#define SEG  (BATCH*NSEQ*DM)   // 1572864 floats = 6.29 MB
#define QT   8                 // query rows per attention block

// ---------------------------------------------------------------- transpose
// x[b][c][n] -> xT[b][n][c]  (residual input, coalesced for the LN epilogue)
__global__ __launch_bounds__(256) void transpose_k(const float* __restrict__ x,
                                                   float* __restrict__ xT) {
  __shared__ float tile[32][33];
  int b  = blockIdx.z;
  int cB = blockIdx.y * 32;
  int nB = blockIdx.x * 32;
  int tx = threadIdx.x & 31, ty = threadIdx.x >> 5;   // ty 0..7
#pragma unroll
  for (int i = 0; i < 4; i++)
    tile[ty + i*8][tx] = x[((size_t)b*DM + cB + ty + i*8)*NSEQ + nB + tx];
  __syncthreads();
#pragma unroll
  for (int i = 0; i < 4; i++)
    xT[((size_t)b*NSEQ + nB + ty + i*8)*DM + cB + tx] = tile[tx][ty + i*8];
}

// ---------------------------------------------------------------- projections
// y[b,o,n] = sum_c x[b,c,n]*w[o,c] + bias[o];  stored as [b][h][n][d] (o=h*128+d)
// grid: (N/256, 384/32, B*3), block 256. Per block: 32 o x 256 n.
__global__ __launch_bounds__(256) void proj_k(const float* __restrict__ x,
    const float* __restrict__ wq, const float* __restrict__ bq,
    const float* __restrict__ wk, const float* __restrict__ bk,
    const float* __restrict__ wv, const float* __restrict__ bv,
    float* __restrict__ Qo, float* __restrict__ Ko, float* __restrict__ Vo) {
  __shared__ float xs[32][256];   // 32 KiB
  int t  = threadIdx.x;
  int nB = blockIdx.x * 256;
  int oB = blockIdx.y * 32;
  int bz = blockIdx.z;
  int b = bz / 3, pj = bz % 3;
  const float* w    = (pj == 0) ? wq : (pj == 1) ? wk : wv;
  const float* bias = (pj == 0) ? bq : (pj == 1) ? bk : bv;
  float* outp       = (pj == 0) ? Qo : (pj == 1) ? Ko : Vo;

  float acc[32];
#pragma unroll
  for (int o = 0; o < 32; o++) acc[o] = 0.f;

  for (int cB2 = 0; cB2 < DM; cB2 += 32) {
#pragma unroll
    for (int cc = 0; cc < 32; cc++)
      xs[cc][t] = x[((size_t)b*DM + cB2 + cc)*NSEQ + nB + t];   // coalesced
    __syncthreads();
    float xr[32];
#pragma unroll
    for (int cc = 0; cc < 32; cc++) xr[cc] = xs[cc][t];         // conflict-free
#pragma unroll
    for (int o = 0; o < 32; o++) {
#pragma unroll
      for (int cc = 0; cc < 32; cc++)   // w uniform -> s_load; xr in VGPRs
        acc[o] = fmaf(w[(size_t)(oB + o)*DM + cB2 + cc], xr[cc], acc[o]);
    }
    __syncthreads();
  }

  int h  = oB >> 7;            // head (oB is a multiple of 32; 32 o's stay in one head)
  int dB = oB & 127;
  int n  = nB + t;
  size_t base = ((size_t)(b*NH + h)*NSEQ + n)*DK + dB;
#pragma unroll
  for (int o4 = 0; o4 < 8; o4++) {
    float4 v4;
    v4.x = acc[o4*4+0] + bias[oB + o4*4+0];
    v4.y = acc[o4*4+1] + bias[oB + o4*4+1];
    v4.z = acc[o4*4+2] + bias[oB + o4*4+2];
    v4.w = acc[o4*4+3] + bias[oB + o4*4+3];
    *(float4*)(&outp[base + o4*4]) = v4;   // per-lane 128B contiguous chunk
  }
}

// ---------------------------------------------------------------- entmax Newton
// Solve sum_k max(z_k - tau, 0)^2 = 1 on a 2048-float LDS row.
// f convex decreasing; start tau = max-1 (f>=1) -> monotone Newton from the left.
__device__ __forceinline__ float newton_tau(const float* zr, float m, int lane) {
  float t = m - 1.0f;
  for (int it = 0; it < 16; ++it) {
    float f = 0.f, g = 0.f;
#pragma unroll
    for (int c = 0; c < 8; c++) {
      float4 z4 = *(const float4*)(zr + c*256 + lane*4);
      float d;
      d = z4.x - t; d = fmaxf(d, 0.f); f = fmaf(d, d, f); g += d;
      d = z4.y - t; d = fmaxf(d, 0.f); f = fmaf(d, d, f); g += d;
      d = z4.z - t; d = fmaxf(d, 0.f); f = fmaf(d, d, f); g += d;
      d = z4.w - t; d = fmaxf(d, 0.f); f = fmaf(d, d, f); g += d;
    }
#pragma unroll
    for (int off = 32; off > 0; off >>= 1) {
      f += __shfl_xor(f, off);
      g += __shfl_xor(g, off);
    }
    t += (f - 1.0f) / (2.0f * fmaxf(g, 1e-12f));   // g >= sqrt(f) ~ 1, safe
  }
  return t;
}

// ---------------------------------------------------------------- fused attention
// One block = 8 query rows of one (b,h). 4 waves, 2 rows/wave.
// P1: energy rows -> LDS. P2: Newton tau per row. P3: z -> p^2 in place.
// P4: PV with k-segment partitioning (each V element read once/block) + LDS reduce.
__global__ __launch_bounds__(256) void attn_k(const float* __restrict__ Q,
    const float* __restrict__ K, const float* __restrict__ V,
    float* __restrict__ AO) {
  __shared__ float zbuf[QT][NSEQ];   // 64 KiB exactly
  int tid  = threadIdx.x;
  int lane = tid & 63;
  int wave = tid >> 6;
  int tpb  = NSEQ / QT;              // 256 tiles per (b,h)
  int bh    = blockIdx.x / tpb;
  int qtile = blockIdx.x % tpb;
  int qbase = qtile * QT;
  const float* Kb = K + (size_t)bh*NSEQ*DK;
  const float* Vb = V + (size_t)bh*NSEQ*DK;
  const float* Qb = Q + (size_t)bh*NSEQ*DK;
  int row0 = wave * 2;
  const float zscale = 0.044194173824159216f;   // (1/sqrt(128)) * 0.5  (entmax z = e/2)

  // ---- P1: energies for this wave's 2 rows; each lane owns 8 k's per j-iter
  float vmax0 = -1e30f, vmax1 = -1e30f;
  const float* qp0 = Qb + (size_t)(qbase + row0)*DK;
  const float* qp1 = qp0 + DK;
  for (int j = 0; j < 4; j++) {
    int k0 = j*512 + lane*8;
    float a0[8], a1[8];
#pragma unroll
    for (int i = 0; i < 8; i++) { a0[i] = 0.f; a1[i] = 0.f; }
    for (int d = 0; d < DK; d += 4) {
      float4 q0 = *(const float4*)(qp0 + d);   // broadcast, L1-hot
      float4 q1 = *(const float4*)(qp1 + d);
#pragma unroll
      for (int i = 0; i < 8; i++) {
        float4 kv = *(const float4*)(Kb + (size_t)(k0 + i)*DK + d);
        a0[i] = fmaf(q0.x, kv.x, a0[i]); a0[i] = fmaf(q0.y, kv.y, a0[i]);
        a0[i] = fmaf(q0.z, kv.z, a0[i]); a0[i] = fmaf(q0.w, kv.w, a0[i]);
        a1[i] = fmaf(q1.x, kv.x, a1[i]); a1[i] = fmaf(q1.y, kv.y, a1[i]);
        a1[i] = fmaf(q1.z, kv.z, a1[i]); a1[i] = fmaf(q1.w, kv.w, a1[i]);
      }
    }
#pragma unroll
    for (int i = 0; i < 8; i++) {
      a0[i] *= zscale; a1[i] *= zscale;
      vmax0 = fmaxf(vmax0, a0[i]); vmax1 = fmaxf(vmax1, a1[i]);
    }
    *(float4*)(&zbuf[row0  ][k0  ]) = make_float4(a0[0], a0[1], a0[2], a0[3]);
    *(float4*)(&zbuf[row0  ][k0+4]) = make_float4(a0[4], a0[5], a0[6], a0[7]);
    *(float4*)(&zbuf[row0+1][k0  ]) = make_float4(a1[0], a1[1], a1[2], a1[3]);
    *(float4*)(&zbuf[row0+1][k0+4]) = make_float4(a1[4], a1[5], a1[6], a1[7]);
  }
#pragma unroll
  for (int off = 32; off > 0; off >>= 1) {
    vmax0 = fmaxf(vmax0, __shfl_xor(vmax0, off));
    vmax1 = fmaxf(vmax1, __shfl_xor(vmax1, off));
  }

  // ---- P2: per-row Newton (wave-local rows; within-wave LDS ordering is in-order)
  float tau0 = newton_tau(&zbuf[row0  ][0], vmax0, lane);
  float tau1 = newton_tau(&zbuf[row0+1][0], vmax1, lane);

  // ---- P3: z -> attn = max(z-tau,0)^2, in place
#pragma unroll
  for (int r = 0; r < 2; r++) {
    float tt = (r == 0) ? tau0 : tau1;
    float* zr = &zbuf[row0 + r][0];
#pragma unroll
    for (int c = 0; c < 8; c++) {
      float4 z4 = *(float4*)(zr + c*256 + lane*4);
      float d;
      d = fmaxf(z4.x - tt, 0.f); z4.x = d*d;
      d = fmaxf(z4.y - tt, 0.f); z4.y = d*d;
      d = fmaxf(z4.z - tt, 0.f); z4.z = d*d;
      d = fmaxf(z4.w - tt, 0.f); z4.w = d*d;
      *(float4*)(zr + c*256 + lane*4) = z4;
    }
  }
  __syncthreads();

  // ---- P4: PV. thread = (d-chunk = tid&31, k-segment = tid>>5); V read once/block.
  int d4   = (tid & 31) * 4;
  int kseg = tid >> 5;
  float4 acc[QT];
#pragma unroll
  for (int q = 0; q < QT; q++) acc[q] = make_float4(0.f, 0.f, 0.f, 0.f);
  for (int k = kseg*256; k < kseg*256 + 256; k += 4) {
    float4 a4[QT];
#pragma unroll
    for (int q = 0; q < QT; q++) a4[q] = *(const float4*)(&zbuf[q][k]);  // broadcast
#pragma unroll
    for (int i = 0; i < 4; i++) {
      float4 vv = *(const float4*)(Vb + (size_t)(k + i)*DK + d4);
#pragma unroll
      for (int q = 0; q < QT; q++) {
        float a = (i == 0) ? a4[q].x : (i == 1) ? a4[q].y : (i == 2) ? a4[q].z : a4[q].w;
        acc[q].x = fmaf(a, vv.x, acc[q].x);
        acc[q].y = fmaf(a, vv.y, acc[q].y);
        acc[q].z = fmaf(a, vv.z, acc[q].z);
        acc[q].w = fmaf(a, vv.w, acc[q].w);
      }
    }
  }
  __syncthreads();                     // all reads of attn done; reuse zbuf
  float* pb = &zbuf[0][0];             // partials: [kseg][q][128]
#pragma unroll
  for (int q = 0; q < QT; q++)
    *(float4*)(&pb[(kseg*QT + q)*DK + d4]) = acc[q];
  __syncthreads();

  // reduce 8 k-segments; write AO[b][n][h*128+d]
  int qo = tid >> 5;
  int dd = (tid & 31) * 4;
  float4 s = make_float4(0.f, 0.f, 0.f, 0.f);
#pragma unroll
  for (int sg = 0; sg < 8; sg++) {
    float4 p = *(const float4*)(&pb[(sg*QT + qo)*DK + dd]);
    s.x += p.x; s.y += p.y; s.z += p.z; s.w += p.w;
  }
  int b = bh / NH, h = bh % NH;
  size_t obase = ((size_t)b*NSEQ + qbase + qo)*DM + h*DK + dd;
  *(float4*)(&AO[obase]) = s;
}

// ---------------------------------------------------------------- LN + residual
// out[row][c] = xT[row][c] + a[c]*(AO-mean)/(std_bessel+eps) + b[c];  row = b*N+n
__global__ __launch_bounds__(256) void ln_k(const float* __restrict__ AO,
    const float* __restrict__ xT, const float* __restrict__ ga,
    const float* __restrict__ gb, float* __restrict__ outp) {
  int lane = threadIdx.x & 63;
  int wave = threadIdx.x >> 6;
  int row  = blockIdx.x * 4 + wave;
  const float* ao = AO + (size_t)row*DM;
  float2 c0 = *(const float2*)(ao + lane*2);
  float2 c1 = *(const float2*)(ao + 128 + lane*2);
  float2 c2 = *(const float2*)(ao + 256 + lane*2);
  float s  = c0.x + c0.y + c1.x + c1.y + c2.x + c2.y;
  float ss = c0.x*c0.x + c0.y*c0.y + c1.x*c1.x + c1.y*c1.y + c2.x*c2.x + c2.y*c2.y;
#pragma unroll
  for (int off = 32; off > 0; off >>= 1) {
    s  += __shfl_xor(s,  off);
    ss += __shfl_xor(ss, off);
  }
  float mean = s * (1.0f / 384.0f);
  float var  = (ss - 384.0f*mean*mean) * (1.0f / 383.0f);   // Bessel (n-1)
  var = fmaxf(var, 0.f);
  float inv = 1.0f / (sqrtf(var) + 1e-6f);                  // eps added to STD
  const float* xr = xT + (size_t)row*DM;
  float* op = outp + (size_t)row*DM;
#pragma unroll
  for (int ch = 0; ch < 3; ch++) {
    int i0 = ch*128 + lane*2;
    float2 g  = *(const float2*)(ga + i0);
    float2 bb = *(const float2*)(gb + i0);
    float2 xv = *(const float2*)(xr + i0);
    float2 av = (ch == 0) ? c0 : (ch == 1) ? c1 : c2;
    float2 o;
    o.x = g.x*(av.x - mean)*inv + bb.x + xv.x;
    o.y = g.y*(av.y - mean)*inv + bb.y + xv.y;
    *(float2*)(op + i0) = o;
  }
}

// ---------------------------------------------------------------- launch
extern "C" void kernel_launch(void* const* d_in, const int* in_sizes, int n_in,
                              void* d_out, int out_size, void* d_ws, size_t ws_size,
                              hipStream_t stream) {
  const float* x  = (const float*)d_in[0];
  const float* wq = (const float*)d_in[1];
  const float* bq = (const float*)d_in[2];
  const float* wk = (const float*)d_in[3];
  const float* bk = (const float*)d_in[4];
  const float* wv = (const float*)d_in[5];
  const float* bv = (const float*)d_in[6];
  const float* la = (const float*)d_in[7];
  const float* lb = (const float*)d_in[8];
  float* out = (float*)d_out;
  float* ws  = (float*)d_ws;
  // workspace: xT | Q | K | V | AO  (5 * 6.29 MB = 31.5 MB)
  float* xT = ws;
  float* Qb = ws + (size_t)SEG;
  float* Kb = ws + (size_t)2*SEG;
  float* Vb = ws + (size_t)3*SEG;
  float* AO = ws + (size_t)4*SEG;

  hipLaunchKernelGGL(transpose_k, dim3(NSEQ/32, DM/32, BATCH), dim3(256), 0, stream, x, xT);
  hipLaunchKernelGGL(proj_k, dim3(NSEQ/256, DM/32, BATCH*3), dim3(256), 0, stream,
                     x, wq, bq, wk, bk, wv, bv, Qb, Kb, Vb);
  hipLaunchKernelGGL(attn_k, dim3(BATCH*NH*NSEQ/QT), dim3(256), 0, stream, Qb, Kb, Vb, AO);
  hipLaunchKernelGGL(ln_k, dim3(BATCH*NSEQ/4), dim3(256), 0, stream, AO, xT, la, lb, out);
}

// Round 2
// 406.924 us; speedup vs baseline: 4.5336x; 4.5336x over previous
//
#include <hip/hip_runtime.h>
#include <math.h>

// HieraFormer fused block: QKV proj (fp32 VALU, bf16 out) -> MFMA entmax1.5
// attention (z in registers, distributed Newton) -> LN+residual.
// B=2, D_MODEL=384, H=3, D_K=128, N=2048.
#define DM   384
#define NH   3
#define DK   128
#define NSEQ 2048
#define BATCH 2
#define SEG  (BATCH*NSEQ*DM)   // 1572864 elements

typedef __attribute__((ext_vector_type(8))) short     bf16x8;
typedef __attribute__((ext_vector_type(8))) unsigned short us8;
typedef __attribute__((ext_vector_type(4))) float     f32x4;

__device__ __forceinline__ unsigned short f2bf(float f) {
  unsigned u = __builtin_bit_cast(unsigned, f);
  u += 0x7FFFu + ((u >> 16) & 1u);          // RNE
  return (unsigned short)(u >> 16);
}

// ---------------------------------------------------------------- transpose
// x[b][c][n] -> xT[b][n][c]  (residual input for the LN epilogue)
__global__ __launch_bounds__(256) void transpose_k(const float* __restrict__ x,
                                                   float* __restrict__ xT) {
  __shared__ float tile[32][33];
  int b  = blockIdx.z;
  int cB = blockIdx.y * 32;
  int nB = blockIdx.x * 32;
  int tx = threadIdx.x & 31, ty = threadIdx.x >> 5;
#pragma unroll
  for (int i = 0; i < 4; i++)
    tile[ty + i*8][tx] = x[((size_t)b*DM + cB + ty + i*8)*NSEQ + nB + tx];
  __syncthreads();
#pragma unroll
  for (int i = 0; i < 4; i++)
    xT[((size_t)b*NSEQ + nB + ty + i*8)*DM + cB + tx] = tile[tx][ty + i*8];
}

// ---------------------------------------------------------------- projections
// y[b,o,n] = sum_c x[b,c,n]*w[o,c] + bias[o]
// Q,K stored bf16 [b][h][n][d]; V stored bf16 transposed VT [b][h][d][n].
__global__ __launch_bounds__(256) void proj_k(const float* __restrict__ x,
    const float* __restrict__ wq, const float* __restrict__ bq,
    const float* __restrict__ wk, const float* __restrict__ bk,
    const float* __restrict__ wv, const float* __restrict__ bv,
    unsigned short* __restrict__ Qo, unsigned short* __restrict__ Ko,
    unsigned short* __restrict__ VTo) {
  __shared__ float xs[32][256];
  int t  = threadIdx.x;
  int nB = blockIdx.x * 256;
  int oB = blockIdx.y * 32;
  int bz = blockIdx.z;
  int b = bz / 3, pj = bz % 3;
  const float* w    = (pj == 0) ? wq : (pj == 1) ? wk : wv;
  const float* bias = (pj == 0) ? bq : (pj == 1) ? bk : bv;

  float acc[32];
#pragma unroll
  for (int o = 0; o < 32; o++) acc[o] = 0.f;

  for (int cB2 = 0; cB2 < DM; cB2 += 32) {
#pragma unroll
    for (int cc = 0; cc < 32; cc++)
      xs[cc][t] = x[((size_t)b*DM + cB2 + cc)*NSEQ + nB + t];   // coalesced
    __syncthreads();
    float xr[32];
#pragma unroll
    for (int cc = 0; cc < 32; cc++) xr[cc] = xs[cc][t];
#pragma unroll
    for (int o = 0; o < 32; o++) {
#pragma unroll
      for (int cc = 0; cc < 32; cc++)   // w uniform -> scalar loads
        acc[o] = fmaf(w[(size_t)(oB + o)*DM + cB2 + cc], xr[cc], acc[o]);
    }
    __syncthreads();
  }

  int h  = oB >> 7;
  int dB = oB & 127;
  int n  = nB + t;
  unsigned short ub[32];
#pragma unroll
  for (int o = 0; o < 32; o++) ub[o] = f2bf(acc[o] + bias[oB + o]);

  if (pj < 2) {              // Q or K: [b,h,n,d]
    unsigned short* dst = ((pj == 0) ? Qo : Ko)
                        + ((size_t)(b*NH + h)*NSEQ + n)*DK + dB;
#pragma unroll
    for (int o8 = 0; o8 < 4; o8++) {
      us8 v;
#pragma unroll
      for (int j = 0; j < 8; j++) v[j] = ub[o8*8 + j];
      *(us8*)(dst + o8*8) = v;
    }
  } else {                   // V transposed: VT[b,h,d,n]
#pragma unroll
    for (int o = 0; o < 32; o++)
      VTo[((size_t)(b*NH + h)*DK + dB + o)*NSEQ + n] = ub[o];   // coalesced over t
  }
}

// ---------------------------------------------------------------- MFMA attention
// Block = 16 q-rows of one (b,h); 512 threads = 8 waves; wave w owns k-cols
// [w*256, w*256+256). z tile lives in C-frags (64 f32/lane). Distributed Newton.
__global__ __launch_bounds__(512, 4) void attn_k(const unsigned short* __restrict__ Qb,
    const unsigned short* __restrict__ Kb, const unsigned short* __restrict__ VTb,
    float* __restrict__ AO) {
  __shared__ __align__(16) char pool[8*16*264*2];   // pbuf (ushort[8][16][264]) then obuf (float[8][16][128])
  __shared__ float2 fgbuf[2][8][16];

  int tid = threadIdx.x, lane = tid & 63, w = tid >> 6;
  int g = lane >> 4, li = lane & 15;
  int qtile = blockIdx.x, bh = blockIdx.y;
  int qbase = qtile * 16;
  const unsigned short* Qh  = Qb  + (size_t)bh * NSEQ * DK;
  const unsigned short* Kh  = Kb  + (size_t)bh * NSEQ * DK;
  const unsigned short* VTh = VTb + (size_t)bh * DK * NSEQ;
  int kc = w * 256;

  // ---- Q A-frags (rows qbase..qbase+15), reused over all k-tiles
  bf16x8 aq[4];
  {
    const unsigned short* qp = Qh + (size_t)(qbase + li) * DK + g * 8;
#pragma unroll
    for (int db = 0; db < 4; db++) aq[db] = *(const bf16x8*)(qp + db * 32);
  }

  // ---- P1: z-frags via MFMA.  zacc[t] = Q[16x128] . K^T[128 x 16]  (k-tile t)
  f32x4 zacc[16];
#pragma unroll
  for (int t = 0; t < 16; t++) zacc[t] = (f32x4){0.f, 0.f, 0.f, 0.f};
  for (int t = 0; t < 16; t++) {
    const unsigned short* kp = Kh + (size_t)(kc + t*16 + li) * DK + g * 8;
#pragma unroll
    for (int db = 0; db < 4; db++) {
      bf16x8 bk = *(const bf16x8*)(kp + db * 32);
      zacc[t] = __builtin_amdgcn_mfma_f32_16x16x32_bf16(aq[db], bk, zacc[t], 0, 0, 0);
    }
  }
  // z = dot * 0.5/sqrt(128); per-lane row max (rows g*4+r over this wave's cols)
  const float zs = 0.044194173824159216f;
  float mx[4] = {-1e30f, -1e30f, -1e30f, -1e30f};
#pragma unroll
  for (int t = 0; t < 16; t++) {
#pragma unroll
    for (int r = 0; r < 4; r++) {
      float z = zacc[t][r] * zs;
      zacc[t][r] = z;
      mx[r] = fmaxf(mx[r], z);
    }
  }
#pragma unroll
  for (int off = 8; off >= 1; off >>= 1)
#pragma unroll
    for (int r = 0; r < 4; r++) mx[r] = fmaxf(mx[r], __shfl_xor(mx[r], off));
  if (li == 0) {
#pragma unroll
    for (int r = 0; r < 4; r++) fgbuf[1][w][g*4 + r] = make_float2(mx[r], 0.f);
  }
  __syncthreads();
  float tau[4];
#pragma unroll
  for (int r = 0; r < 4; r++) {
    float m = -1e30f;
#pragma unroll
    for (int ww = 0; ww < 8; ww++) m = fmaxf(m, fgbuf[1][ww][g*4 + r].x);
    tau[r] = m - 1.0f;   // f(tau0) >= 1 -> monotone Newton from the left
  }

  // ---- P2: distributed Newton for sum_k (z-tau)_+^2 = 1
  for (int it = 0; it < 16; ++it) {
    float f[4] = {0.f, 0.f, 0.f, 0.f}, gg[4] = {0.f, 0.f, 0.f, 0.f};
#pragma unroll
    for (int t = 0; t < 16; t++) {
#pragma unroll
      for (int r = 0; r < 4; r++) {
        float d = fmaxf(zacc[t][r] - tau[r], 0.f);
        f[r] = fmaf(d, d, f[r]);
        gg[r] += d;
      }
    }
#pragma unroll
    for (int off = 8; off >= 1; off >>= 1)
#pragma unroll
      for (int r = 0; r < 4; r++) { f[r] += __shfl_xor(f[r], off); gg[r] += __shfl_xor(gg[r], off); }
    int p = it & 1;
    if (li == 0) {
#pragma unroll
      for (int r = 0; r < 4; r++) fgbuf[p][w][g*4 + r] = make_float2(f[r], gg[r]);
    }
    __syncthreads();
#pragma unroll
    for (int r = 0; r < 4; r++) {
      float fs = 0.f, gs = 0.f;
#pragma unroll
      for (int ww = 0; ww < 8; ww++) {
        float2 v = fgbuf[p][ww][g*4 + r];
        fs += v.x; gs += v.y;
      }
      tau[r] += (fs - 1.0f) / (2.0f * fmaxf(gs, 1e-12f));  // gs >= sqrt(fs) ~ 1
    }
  }

  // ---- P3: p = (z-tau)_+^2 -> bf16 -> LDS (wave-private region; no barrier needed)
  unsigned short* pbuf = (unsigned short*)pool + (size_t)w * 16 * 264;
#pragma unroll
  for (int t = 0; t < 16; t++) {
    int c = t * 16 + li;
#pragma unroll
    for (int r = 0; r < 4; r++) {
      float d = fmaxf(zacc[t][r] - tau[r], 0.f);
      pbuf[(g*4 + r) * 264 + c] = f2bf(d * d);
    }
  }

  // ---- P4: PV via MFMA over this wave's k-chunk. A = P (LDS), B = V^T (global).
  bf16x8 ap[8];
#pragma unroll
  for (int kk = 0; kk < 8; kk++)
    ap[kk] = *(const bf16x8*)&pbuf[li * 264 + kk * 32 + g * 8];
  f32x4 oacc[8];
#pragma unroll
  for (int dt = 0; dt < 8; dt++) oacc[dt] = (f32x4){0.f, 0.f, 0.f, 0.f};
#pragma unroll
  for (int dt = 0; dt < 8; dt++) {
    const unsigned short* vp = VTh + (size_t)(dt*16 + li) * NSEQ + kc + g * 8;
#pragma unroll
    for (int kk = 0; kk < 8; kk++) {
      bf16x8 bv = *(const bf16x8*)(vp + kk * 32);
      oacc[dt] = __builtin_amdgcn_mfma_f32_16x16x32_bf16(ap[kk], bv, oacc[dt], 0, 0, 0);
    }
  }

  // ---- cross-wave reduction of partial O (8 waves x [16 q x 128 d])
  __syncthreads();                       // all pbuf reads done; reuse pool as obuf
  float* obuf = (float*)pool + (size_t)w * 16 * 128;
#pragma unroll
  for (int dt = 0; dt < 8; dt++)
#pragma unroll
    for (int r = 0; r < 4; r++)
      obuf[(g*4 + r)*128 + dt*16 + li] = oacc[dt][r];
  __syncthreads();

  int q = tid >> 5, d4 = (tid & 31) * 4;
  float4 s = make_float4(0.f, 0.f, 0.f, 0.f);
#pragma unroll
  for (int ww = 0; ww < 8; ww++) {
    const float* ob = (const float*)pool + (size_t)ww * 2048 + q * 128 + d4;
    s.x += ob[0]; s.y += ob[1]; s.z += ob[2]; s.w += ob[3];
  }
  int b = bh / NH, h = bh % NH;
  *(float4*)&AO[((size_t)b*NSEQ + qbase + q)*DM + h*DK + d4] = s;
}

// ---------------------------------------------------------------- LN + residual
__global__ __launch_bounds__(256) void ln_k(const float* __restrict__ AO,
    const float* __restrict__ xT, const float* __restrict__ ga,
    const float* __restrict__ gb, float* __restrict__ outp) {
  int lane = threadIdx.x & 63;
  int wave = threadIdx.x >> 6;
  int row  = blockIdx.x * 4 + wave;
  const float* ao = AO + (size_t)row*DM;
  float2 c0 = *(const float2*)(ao + lane*2);
  float2 c1 = *(const float2*)(ao + 128 + lane*2);
  float2 c2 = *(const float2*)(ao + 256 + lane*2);
  float s  = c0.x + c0.y + c1.x + c1.y + c2.x + c2.y;
  float ss = c0.x*c0.x + c0.y*c0.y + c1.x*c1.x + c1.y*c1.y + c2.x*c2.x + c2.y*c2.y;
#pragma unroll
  for (int off = 32; off > 0; off >>= 1) {
    s  += __shfl_xor(s,  off);
    ss += __shfl_xor(ss, off);
  }
  float mean = s * (1.0f / 384.0f);
  float var  = (ss - 384.0f*mean*mean) * (1.0f / 383.0f);   // Bessel (n-1)
  var = fmaxf(var, 0.f);
  float inv = 1.0f / (sqrtf(var) + 1e-6f);                  // eps added to STD
  const float* xr = xT + (size_t)row*DM;
  float* op = outp + (size_t)row*DM;
#pragma unroll
  for (int ch = 0; ch < 3; ch++) {
    int i0 = ch*128 + lane*2;
    float2 g  = *(const float2*)(ga + i0);
    float2 bb = *(const float2*)(gb + i0);
    float2 xv = *(const float2*)(xr + i0);
    float2 av = (ch == 0) ? c0 : (ch == 1) ? c1 : c2;
    float2 o;
    o.x = g.x*(av.x - mean)*inv + bb.x + xv.x;
    o.y = g.y*(av.y - mean)*inv + bb.y + xv.y;
    *(float2*)(op + i0) = o;
  }
}

// ---------------------------------------------------------------- launch
extern "C" void kernel_launch(void* const* d_in, const int* in_sizes, int n_in,
                              void* d_out, int out_size, void* d_ws, size_t ws_size,
                              hipStream_t stream) {
  const float* x  = (const float*)d_in[0];
  const float* wq = (const float*)d_in[1];
  const float* bq = (const float*)d_in[2];
  const float* wk = (const float*)d_in[3];
  const float* bk = (const float*)d_in[4];
  const float* wv = (const float*)d_in[5];
  const float* bv = (const float*)d_in[6];
  const float* la = (const float*)d_in[7];
  const float* lb = (const float*)d_in[8];
  float* out = (float*)d_out;

  // workspace: xT f32 | AO f32 | Qb bf16 | Kb bf16 | VT bf16  (~22 MB)
  char* wsb = (char*)d_ws;
  float* xT = (float*)wsb;
  float* AO = (float*)(wsb + (size_t)SEG*4);
  unsigned short* Qb = (unsigned short*)(wsb + (size_t)SEG*8);
  unsigned short* Kb = (unsigned short*)(wsb + (size_t)SEG*8 + (size_t)SEG*2);
  unsigned short* VT = (unsigned short*)(wsb + (size_t)SEG*8 + (size_t)SEG*4);

  hipLaunchKernelGGL(transpose_k, dim3(NSEQ/32, DM/32, BATCH), dim3(256), 0, stream, x, xT);
  hipLaunchKernelGGL(proj_k, dim3(NSEQ/256, DM/32, BATCH*3), dim3(256), 0, stream,
                     x, wq, bq, wk, bk, wv, bv, Qb, Kb, VT);
  hipLaunchKernelGGL(attn_k, dim3(NSEQ/16, BATCH*NH), dim3(512), 0, stream, Qb, Kb, VT, AO);
  hipLaunchKernelGGL(ln_k, dim3(BATCH*NSEQ/4), dim3(256), 0, stream, AO, xT, la, lb, out);
}

// Round 3
// 183.230 us; speedup vs baseline: 10.0685x; 2.2208x over previous
//
#include <hip/hip_runtime.h>
#include <math.h>

// HieraFormer fused block: MFMA QKV proj -> MFMA entmax1.5 attention -> LN+residual.
// B=2, D_MODEL=384, H=3, D_K=128, N=2048.
#define DM   384
#define NH   3
#define DK   128
#define NSEQ 2048
#define BATCH 2
#define NTOK (BATCH*NSEQ)      // 4096
#define SEG  (BATCH*NSEQ*DM)   // 1572864 elements

typedef __attribute__((ext_vector_type(8))) short     bf16x8;
typedef __attribute__((ext_vector_type(8))) unsigned short us8;
typedef __attribute__((ext_vector_type(4))) float     f32x4;

__device__ __forceinline__ unsigned short f2bf(float f) {
  unsigned u = __builtin_bit_cast(unsigned, f);
  u += 0x7FFFu + ((u >> 16) & 1u);          // RNE
  return (unsigned short)(u >> 16);
}

// ---------------------------------------------------------------- transpose
// x[b][c][n] -> xT[b][n][c] (f32, LN residual)  and  xbf[tok][c] (bf16, GEMM operand)
__global__ __launch_bounds__(256) void transpose_k(const float* __restrict__ x,
                                                   float* __restrict__ xT,
                                                   unsigned short* __restrict__ xbf) {
  __shared__ float tile[32][33];
  int b  = blockIdx.z;
  int cB = blockIdx.y * 32;
  int nB = blockIdx.x * 32;
  int tx = threadIdx.x & 31, ty = threadIdx.x >> 5;
#pragma unroll
  for (int i = 0; i < 4; i++)
    tile[ty + i*8][tx] = x[((size_t)b*DM + cB + ty + i*8)*NSEQ + nB + tx];
  __syncthreads();
#pragma unroll
  for (int i = 0; i < 4; i++) {
    float v = tile[tx][ty + i*8];
    size_t row = (size_t)b*NSEQ + nB + ty + i*8;
    xT [row*DM + cB + tx] = v;
    xbf[row*DM + cB + tx] = f2bf(v);
  }
}

// ---------------------------------------------------------------- weight convert
__global__ __launch_bounds__(256) void wconv_k(const float* __restrict__ wq,
    const float* __restrict__ wk, const float* __restrict__ wv,
    unsigned short* __restrict__ wbf) {
  int pj = blockIdx.y;
  const float* src = (pj == 0) ? wq : (pj == 1) ? wk : wv;
  int i = (blockIdx.x * 256 + threadIdx.x) * 4;        // DM*DM = 147456, grid.x = 144
  float4 v = *(const float4*)(src + i);
  ushort4 o;
  o.x = f2bf(v.x); o.y = f2bf(v.y); o.z = f2bf(v.z); o.w = f2bf(v.w);
  *(ushort4*)(wbf + (size_t)pj*DM*DM + i) = o;
}

// ---------------------------------------------------------------- MFMA projections
// Generic D[m][n] = sum_c A[m][c]*B[n][c].
// pj<2 (Q,K): A = w (m=o), B = x (n=tok) -> lane holds 4 consecutive d  -> ushort4 into Q[n][d]
// pj=2  (V) : A = x (m=tok), B = w (n=o) -> lane holds 4 consecutive tok -> ushort4 into VT[d][n]
// Block: 256 thr = 4 waves (2x2), wave tile 64x64 = 4x4 frags of 16x16x32. No LDS.
__global__ __launch_bounds__(256) void proj_mfma_k(
    const unsigned short* __restrict__ xbf,   // [NTOK][DM]
    const unsigned short* __restrict__ wbf,   // [3][DM][DM]
    const float* __restrict__ bq, const float* __restrict__ bk, const float* __restrict__ bv,
    unsigned short* __restrict__ Qo, unsigned short* __restrict__ Ko,
    unsigned short* __restrict__ VTo) {
  int tid = threadIdx.x, lane = tid & 63, w = tid >> 6;
  int g = lane >> 4, li = lane & 15;
  int wr = w >> 1, wc = w & 1;
  int h  = blockIdx.y;                       // o-tile (128 wide) == head
  int pj = blockIdx.z;
  const unsigned short* wp0 = wbf + (size_t)pj * DM * DM;
  const float* bias = (pj == 0) ? bq : (pj == 1) ? bk : bv;

  const unsigned short *Am, *Bn;
  int mB, nB;
  if (pj < 2) { Am = wp0; mB = h*128 + wr*64;          Bn = xbf; nB = blockIdx.x*128 + wc*64; }
  else        { Am = xbf; mB = blockIdx.x*128 + wr*64; Bn = wp0; nB = h*128 + wc*64; }

  f32x4 acc[4][4];
#pragma unroll
  for (int fi = 0; fi < 4; fi++)
#pragma unroll
    for (int fj = 0; fj < 4; fj++) acc[fi][fj] = (f32x4){0.f, 0.f, 0.f, 0.f};

#pragma unroll 2
  for (int ks = 0; ks < DM/32; ks++) {
    bf16x8 af[4], bf[4];
#pragma unroll
    for (int fi = 0; fi < 4; fi++)
      af[fi] = *(const bf16x8*)(Am + (size_t)(mB + fi*16 + li)*DM + ks*32 + g*8);
#pragma unroll
    for (int fj = 0; fj < 4; fj++)
      bf[fj] = *(const bf16x8*)(Bn + (size_t)(nB + fj*16 + li)*DM + ks*32 + g*8);
#pragma unroll
    for (int fi = 0; fi < 4; fi++)
#pragma unroll
      for (int fj = 0; fj < 4; fj++)
        acc[fi][fj] = __builtin_amdgcn_mfma_f32_16x16x32_bf16(af[fi], bf[fj], acc[fi][fj], 0, 0, 0);
  }

  if (pj < 2) {
    // frag (fi,fj): rows o0+r (o0 = mB+fi*16+g*4), col tok = nB+fj*16+li
    unsigned short* dst = (pj == 0) ? Qo : Ko;
#pragma unroll
    for (int fi = 0; fi < 4; fi++) {
      int o0 = mB + fi*16 + g*4;
      float4 bb = *(const float4*)(bias + o0);
      int d0 = o0 & 127;
#pragma unroll
      for (int fj = 0; fj < 4; fj++) {
        int tok = nB + fj*16 + li;
        int bb_ = tok >> 11, n = tok & 2047;
        ushort4 v4;
        v4.x = f2bf(acc[fi][fj][0] + bb.x);
        v4.y = f2bf(acc[fi][fj][1] + bb.y);
        v4.z = f2bf(acc[fi][fj][2] + bb.z);
        v4.w = f2bf(acc[fi][fj][3] + bb.w);
        *(ushort4*)(dst + ((size_t)(bb_*NH + h)*NSEQ + n)*DK + d0) = v4;
      }
    }
  } else {
    // frag (fi,fj): rows tok0+r (tok0 = mB+fi*16+g*4), col o = nB+fj*16+li
#pragma unroll
    for (int fj = 0; fj < 4; fj++) {
      int o  = nB + fj*16 + li;
      float bb = bias[o];
      int d  = o & 127;
#pragma unroll
      for (int fi = 0; fi < 4; fi++) {
        int tok0 = mB + fi*16 + g*4;
        int bb_ = tok0 >> 11, n0 = tok0 & 2047;
        ushort4 v4;
        v4.x = f2bf(acc[fi][fj][0] + bb);
        v4.y = f2bf(acc[fi][fj][1] + bb);
        v4.z = f2bf(acc[fi][fj][2] + bb);
        v4.w = f2bf(acc[fi][fj][3] + bb);
        *(ushort4*)(VTo + ((size_t)(bb_*NH + h)*DK + d)*NSEQ + n0) = v4;
      }
    }
  }
}

// ---------------------------------------------------------------- MFMA attention
// Block = 16 q-rows of one (b,h); 512 threads = 8 waves; wave w owns k-cols
// [w*256, w*256+256). z tile lives in C-frags (64 f32/lane). Distributed Newton.
__global__ __launch_bounds__(512, 4) void attn_k(const unsigned short* __restrict__ Qb,
    const unsigned short* __restrict__ Kb, const unsigned short* __restrict__ VTb,
    float* __restrict__ AO) {
  __shared__ __align__(16) char pool[8*16*264*2];   // pbuf (ushort[8][16][264]) then obuf (float[8][16][128])
  __shared__ float2 fgbuf[2][8][16];

  int tid = threadIdx.x, lane = tid & 63, w = tid >> 6;
  int g = lane >> 4, li = lane & 15;
  int qtile = blockIdx.x, bh = blockIdx.y;
  int qbase = qtile * 16;
  const unsigned short* Qh  = Qb  + (size_t)bh * NSEQ * DK;
  const unsigned short* Kh  = Kb  + (size_t)bh * NSEQ * DK;
  const unsigned short* VTh = VTb + (size_t)bh * DK * NSEQ;
  int kc = w * 256;

  // ---- Q A-frags (rows qbase..qbase+15), reused over all k-tiles
  bf16x8 aq[4];
  {
    const unsigned short* qp = Qh + (size_t)(qbase + li) * DK + g * 8;
#pragma unroll
    for (int db = 0; db < 4; db++) aq[db] = *(const bf16x8*)(qp + db * 32);
  }

  // ---- P1: z-frags via MFMA.  zacc[t] = Q[16x128] . K^T[128 x 16]  (k-tile t)
  f32x4 zacc[16];
#pragma unroll
  for (int t = 0; t < 16; t++) zacc[t] = (f32x4){0.f, 0.f, 0.f, 0.f};
  for (int t = 0; t < 16; t++) {
    const unsigned short* kp = Kh + (size_t)(kc + t*16 + li) * DK + g * 8;
#pragma unroll
    for (int db = 0; db < 4; db++) {
      bf16x8 bk = *(const bf16x8*)(kp + db * 32);
      zacc[t] = __builtin_amdgcn_mfma_f32_16x16x32_bf16(aq[db], bk, zacc[t], 0, 0, 0);
    }
  }
  // z = dot * 0.5/sqrt(128); per-lane row max (rows g*4+r over this wave's cols)
  const float zs = 0.044194173824159216f;
  float mx[4] = {-1e30f, -1e30f, -1e30f, -1e30f};
#pragma unroll
  for (int t = 0; t < 16; t++) {
#pragma unroll
    for (int r = 0; r < 4; r++) {
      float z = zacc[t][r] * zs;
      zacc[t][r] = z;
      mx[r] = fmaxf(mx[r], z);
    }
  }
#pragma unroll
  for (int off = 8; off >= 1; off >>= 1)
#pragma unroll
    for (int r = 0; r < 4; r++) mx[r] = fmaxf(mx[r], __shfl_xor(mx[r], off));
  if (li == 0) {
#pragma unroll
    for (int r = 0; r < 4; r++) fgbuf[1][w][g*4 + r] = make_float2(mx[r], 0.f);
  }
  __syncthreads();
  float tau[4];
#pragma unroll
  for (int r = 0; r < 4; r++) {
    float m = -1e30f;
#pragma unroll
    for (int ww = 0; ww < 8; ww++) m = fmaxf(m, fgbuf[1][ww][g*4 + r].x);
    tau[r] = m - 1.0f;   // f(tau0) >= 1 -> monotone Newton from the left
  }

  // ---- P2: distributed Newton for sum_k (z-tau)_+^2 = 1
  for (int it = 0; it < 16; ++it) {
    float f[4] = {0.f, 0.f, 0.f, 0.f}, gg[4] = {0.f, 0.f, 0.f, 0.f};
#pragma unroll
    for (int t = 0; t < 16; t++) {
#pragma unroll
      for (int r = 0; r < 4; r++) {
        float d = fmaxf(zacc[t][r] - tau[r], 0.f);
        f[r] = fmaf(d, d, f[r]);
        gg[r] += d;
      }
    }
#pragma unroll
    for (int off = 8; off >= 1; off >>= 1)
#pragma unroll
      for (int r = 0; r < 4; r++) { f[r] += __shfl_xor(f[r], off); gg[r] += __shfl_xor(gg[r], off); }
    int p = it & 1;
    if (li == 0) {
#pragma unroll
      for (int r = 0; r < 4; r++) fgbuf[p][w][g*4 + r] = make_float2(f[r], gg[r]);
    }
    __syncthreads();
#pragma unroll
    for (int r = 0; r < 4; r++) {
      float fs = 0.f, gs = 0.f;
#pragma unroll
      for (int ww = 0; ww < 8; ww++) {
        float2 v = fgbuf[p][ww][g*4 + r];
        fs += v.x; gs += v.y;
      }
      tau[r] += (fs - 1.0f) / (2.0f * fmaxf(gs, 1e-12f));  // gs >= sqrt(fs) ~ 1
    }
  }

  // ---- P3: p = (z-tau)_+^2 -> bf16 -> LDS (wave-private region; no barrier needed)
  unsigned short* pbuf = (unsigned short*)pool + (size_t)w * 16 * 264;
#pragma unroll
  for (int t = 0; t < 16; t++) {
    int c = t * 16 + li;
#pragma unroll
    for (int r = 0; r < 4; r++) {
      float d = fmaxf(zacc[t][r] - tau[r], 0.f);
      pbuf[(g*4 + r) * 264 + c] = f2bf(d * d);
    }
  }

  // ---- P4: PV via MFMA over this wave's k-chunk. A = P (LDS), B = V^T (global).
  bf16x8 ap[8];
#pragma unroll
  for (int kk = 0; kk < 8; kk++)
    ap[kk] = *(const bf16x8*)&pbuf[li * 264 + kk * 32 + g * 8];
  f32x4 oacc[8];
#pragma unroll
  for (int dt = 0; dt < 8; dt++) oacc[dt] = (f32x4){0.f, 0.f, 0.f, 0.f};
#pragma unroll
  for (int dt = 0; dt < 8; dt++) {
    const unsigned short* vp = VTh + (size_t)(dt*16 + li) * NSEQ + kc + g * 8;
#pragma unroll
    for (int kk = 0; kk < 8; kk++) {
      bf16x8 bv = *(const bf16x8*)(vp + kk * 32);
      oacc[dt] = __builtin_amdgcn_mfma_f32_16x16x32_bf16(ap[kk], bv, oacc[dt], 0, 0, 0);
    }
  }

  // ---- cross-wave reduction of partial O (8 waves x [16 q x 128 d])
  __syncthreads();                       // all pbuf reads done; reuse pool as obuf
  float* obuf = (float*)pool + (size_t)w * 16 * 128;
#pragma unroll
  for (int dt = 0; dt < 8; dt++)
#pragma unroll
    for (int r = 0; r < 4; r++)
      obuf[(g*4 + r)*128 + dt*16 + li] = oacc[dt][r];
  __syncthreads();

  int q = tid >> 5, d4 = (tid & 31) * 4;
  float4 s = make_float4(0.f, 0.f, 0.f, 0.f);
#pragma unroll
  for (int ww = 0; ww < 8; ww++) {
    const float* ob = (const float*)pool + (size_t)ww * 2048 + q * 128 + d4;
    s.x += ob[0]; s.y += ob[1]; s.z += ob[2]; s.w += ob[3];
  }
  int b = bh / NH, h = bh % NH;
  *(float4*)&AO[((size_t)b*NSEQ + qbase + q)*DM + h*DK + d4] = s;
}

// ---------------------------------------------------------------- LN + residual
__global__ __launch_bounds__(256) void ln_k(const float* __restrict__ AO,
    const float* __restrict__ xT, const float* __restrict__ ga,
    const float* __restrict__ gb, float* __restrict__ outp) {
  int lane = threadIdx.x & 63;
  int wave = threadIdx.x >> 6;
  int row  = blockIdx.x * 4 + wave;
  const float* ao = AO + (size_t)row*DM;
  float2 c0 = *(const float2*)(ao + lane*2);
  float2 c1 = *(const float2*)(ao + 128 + lane*2);
  float2 c2 = *(const float2*)(ao + 256 + lane*2);
  float s  = c0.x + c0.y + c1.x + c1.y + c2.x + c2.y;
  float ss = c0.x*c0.x + c0.y*c0.y + c1.x*c1.x + c1.y*c1.y + c2.x*c2.x + c2.y*c2.y;
#pragma unroll
  for (int off = 32; off > 0; off >>= 1) {
    s  += __shfl_xor(s,  off);
    ss += __shfl_xor(ss, off);
  }
  float mean = s * (1.0f / 384.0f);
  float var  = (ss - 384.0f*mean*mean) * (1.0f / 383.0f);   // Bessel (n-1)
  var = fmaxf(var, 0.f);
  float inv = 1.0f / (sqrtf(var) + 1e-6f);                  // eps added to STD
  const float* xr = xT + (size_t)row*DM;
  float* op = outp + (size_t)row*DM;
#pragma unroll
  for (int ch = 0; ch < 3; ch++) {
    int i0 = ch*128 + lane*2;
    float2 g  = *(const float2*)(ga + i0);
    float2 bb = *(const float2*)(gb + i0);
    float2 xv = *(const float2*)(xr + i0);
    float2 av = (ch == 0) ? c0 : (ch == 1) ? c1 : c2;
    float2 o;
    o.x = g.x*(av.x - mean)*inv + bb.x + xv.x;
    o.y = g.y*(av.y - mean)*inv + bb.y + xv.y;
    *(float2*)(op + i0) = o;
  }
}

// ---------------------------------------------------------------- launch
extern "C" void kernel_launch(void* const* d_in, const int* in_sizes, int n_in,
                              void* d_out, int out_size, void* d_ws, size_t ws_size,
                              hipStream_t stream) {
  const float* x  = (const float*)d_in[0];
  const float* wq = (const float*)d_in[1];
  const float* bq = (const float*)d_in[2];
  const float* wk = (const float*)d_in[3];
  const float* bk = (const float*)d_in[4];
  const float* wv = (const float*)d_in[5];
  const float* bv = (const float*)d_in[6];
  const float* la = (const float*)d_in[7];
  const float* lb = (const float*)d_in[8];
  float* out = (float*)d_out;

  // ws: xT f32 | AO f32 | Qb bf16 | Kb bf16 | VT bf16 | xbf bf16 | wbf bf16 (~26.3 MB)
  char* wsb = (char*)d_ws;
  float* xT = (float*)wsb;
  float* AO = (float*)(wsb + (size_t)SEG*4);
  unsigned short* Qb  = (unsigned short*)(wsb + (size_t)SEG*8);
  unsigned short* Kb  = (unsigned short*)(wsb + (size_t)SEG*8 + (size_t)SEG*2);
  unsigned short* VT  = (unsigned short*)(wsb + (size_t)SEG*8 + (size_t)SEG*4);
  unsigned short* xbf = (unsigned short*)(wsb + (size_t)SEG*8 + (size_t)SEG*6);
  unsigned short* wbf = (unsigned short*)(wsb + (size_t)SEG*8 + (size_t)SEG*8);

  hipLaunchKernelGGL(transpose_k, dim3(NSEQ/32, DM/32, BATCH), dim3(256), 0, stream,
                     x, xT, xbf);
  hipLaunchKernelGGL(wconv_k, dim3(DM*DM/1024, 3), dim3(256), 0, stream, wq, wk, wv, wbf);
  hipLaunchKernelGGL(proj_mfma_k, dim3(NTOK/128, NH, 3), dim3(256), 0, stream,
                     xbf, wbf, bq, bk, bv, Qb, Kb, VT);
  hipLaunchKernelGGL(attn_k, dim3(NSEQ/16, BATCH*NH), dim3(512), 0, stream, Qb, Kb, VT, AO);
  hipLaunchKernelGGL(ln_k, dim3(BATCH*NSEQ/4), dim3(256), 0, stream, AO, xT, la, lb, out);
}

// Round 4
// 165.641 us; speedup vs baseline: 11.1376x; 1.1062x over previous
//
#include <hip/hip_runtime.h>
#include <hip/hip_fp16.h>
#include <math.h>

// HieraFormer fused block: MFMA QKV proj -> MFMA entmax1.5 attention
// (fp16 z in LDS, wave-private quadratic-Newton) -> LN+residual.
// B=2, D_MODEL=384, H=3, D_K=128, N=2048.
#define DM   384
#define NH   3
#define DK   128
#define NSEQ 2048
#define BATCH 2
#define NTOK (BATCH*NSEQ)      // 4096
#define SEG  (BATCH*NSEQ*DM)   // 1572864 elements
#define ZPITCH 2056            // halves per z-row (2048 + 8): rows 8 apart alias -> 2-way only
#define NEWTON_IT 10

typedef __attribute__((ext_vector_type(8))) short     bf16x8;
typedef __attribute__((ext_vector_type(8))) unsigned short us8;
typedef __attribute__((ext_vector_type(4))) float     f32x4;
typedef __attribute__((ext_vector_type(8))) _Float16  h8;
typedef __attribute__((ext_vector_type(2))) _Float16  h2v;

#if __has_builtin(__builtin_amdgcn_fdot2)
#define HAVE_FDOT2 1
#else
#define HAVE_FDOT2 0
#endif

__device__ __forceinline__ unsigned short f2bf(float f) {
  unsigned u = __builtin_bit_cast(unsigned, f);
  u += 0x7FFFu + ((u >> 16) & 1u);          // RNE
  return (unsigned short)(u >> 16);
}

// ---------------------------------------------------------------- transpose
__global__ __launch_bounds__(256) void transpose_k(const float* __restrict__ x,
                                                   float* __restrict__ xT,
                                                   unsigned short* __restrict__ xbf) {
  __shared__ float tile[32][33];
  int b  = blockIdx.z;
  int cB = blockIdx.y * 32;
  int nB = blockIdx.x * 32;
  int tx = threadIdx.x & 31, ty = threadIdx.x >> 5;
#pragma unroll
  for (int i = 0; i < 4; i++)
    tile[ty + i*8][tx] = x[((size_t)b*DM + cB + ty + i*8)*NSEQ + nB + tx];
  __syncthreads();
#pragma unroll
  for (int i = 0; i < 4; i++) {
    float v = tile[tx][ty + i*8];
    size_t row = (size_t)b*NSEQ + nB + ty + i*8;
    xT [row*DM + cB + tx] = v;
    xbf[row*DM + cB + tx] = f2bf(v);
  }
}

// ---------------------------------------------------------------- weight convert
__global__ __launch_bounds__(256) void wconv_k(const float* __restrict__ wq,
    const float* __restrict__ wk, const float* __restrict__ wv,
    unsigned short* __restrict__ wbf) {
  int pj = blockIdx.y;
  const float* src = (pj == 0) ? wq : (pj == 1) ? wk : wv;
  int i = (blockIdx.x * 256 + threadIdx.x) * 4;
  float4 v = *(const float4*)(src + i);
  ushort4 o;
  o.x = f2bf(v.x); o.y = f2bf(v.y); o.z = f2bf(v.z); o.w = f2bf(v.w);
  *(ushort4*)(wbf + (size_t)pj*DM*DM + i) = o;
}

// ---------------------------------------------------------------- MFMA projections
// Q,K -> bf16 [b][h][n][d];  V -> fp16 transposed VT [b][h][d][n].
__global__ __launch_bounds__(256) void proj_mfma_k(
    const unsigned short* __restrict__ xbf,   // [NTOK][DM]
    const unsigned short* __restrict__ wbf,   // [3][DM][DM]
    const float* __restrict__ bq, const float* __restrict__ bk, const float* __restrict__ bv,
    unsigned short* __restrict__ Qo, unsigned short* __restrict__ Ko,
    unsigned short* __restrict__ VTo) {      // VT stored as f16 bit-pattern
  int tid = threadIdx.x, lane = tid & 63, w = tid >> 6;
  int g = lane >> 4, li = lane & 15;
  int wr = w >> 1, wc = w & 1;
  int h  = blockIdx.y;
  int pj = blockIdx.z;
  const unsigned short* wp0 = wbf + (size_t)pj * DM * DM;
  const float* bias = (pj == 0) ? bq : (pj == 1) ? bk : bv;

  const unsigned short *Am, *Bn;
  int mB, nB;
  if (pj < 2) { Am = wp0; mB = h*128 + wr*64;          Bn = xbf; nB = blockIdx.x*128 + wc*64; }
  else        { Am = xbf; mB = blockIdx.x*128 + wr*64; Bn = wp0; nB = h*128 + wc*64; }

  f32x4 acc[4][4];
#pragma unroll
  for (int fi = 0; fi < 4; fi++)
#pragma unroll
    for (int fj = 0; fj < 4; fj++) acc[fi][fj] = (f32x4){0.f, 0.f, 0.f, 0.f};

#pragma unroll 2
  for (int ks = 0; ks < DM/32; ks++) {
    bf16x8 af[4], bf[4];
#pragma unroll
    for (int fi = 0; fi < 4; fi++)
      af[fi] = *(const bf16x8*)(Am + (size_t)(mB + fi*16 + li)*DM + ks*32 + g*8);
#pragma unroll
    for (int fj = 0; fj < 4; fj++)
      bf[fj] = *(const bf16x8*)(Bn + (size_t)(nB + fj*16 + li)*DM + ks*32 + g*8);
#pragma unroll
    for (int fi = 0; fi < 4; fi++)
#pragma unroll
      for (int fj = 0; fj < 4; fj++)
        acc[fi][fj] = __builtin_amdgcn_mfma_f32_16x16x32_bf16(af[fi], bf[fj], acc[fi][fj], 0, 0, 0);
  }

  if (pj < 2) {
    unsigned short* dst = (pj == 0) ? Qo : Ko;
#pragma unroll
    for (int fi = 0; fi < 4; fi++) {
      int o0 = mB + fi*16 + g*4;
      float4 bb = *(const float4*)(bias + o0);
      int d0 = o0 & 127;
#pragma unroll
      for (int fj = 0; fj < 4; fj++) {
        int tok = nB + fj*16 + li;
        int bb_ = tok >> 11, n = tok & 2047;
        ushort4 v4;
        v4.x = f2bf(acc[fi][fj][0] + bb.x);
        v4.y = f2bf(acc[fi][fj][1] + bb.y);
        v4.z = f2bf(acc[fi][fj][2] + bb.z);
        v4.w = f2bf(acc[fi][fj][3] + bb.w);
        *(ushort4*)(dst + ((size_t)(bb_*NH + h)*NSEQ + n)*DK + d0) = v4;
      }
    }
  } else {
#pragma unroll
    for (int fj = 0; fj < 4; fj++) {
      int o  = nB + fj*16 + li;
      float bb = bias[o];
      int d  = o & 127;
#pragma unroll
      for (int fi = 0; fi < 4; fi++) {
        int tok0 = mB + fi*16 + g*4;
        int bb_ = tok0 >> 11, n0 = tok0 & 2047;
        ushort4 v4;
        v4.x = __builtin_bit_cast(unsigned short, (_Float16)(acc[fi][fj][0] + bb));
        v4.y = __builtin_bit_cast(unsigned short, (_Float16)(acc[fi][fj][1] + bb));
        v4.z = __builtin_bit_cast(unsigned short, (_Float16)(acc[fi][fj][2] + bb));
        v4.w = __builtin_bit_cast(unsigned short, (_Float16)(acc[fi][fj][3] + bb));
        *(ushort4*)(VTo + ((size_t)(bb_*NH + h)*DK + d)*NSEQ + n0) = v4;
      }
    }
  }
}

// ---------------------------------------------------------------- entmax helpers
// scan f=sum d^2, g=sum d, c=support count over 16 half2 (one row slice)
__device__ __forceinline__ void scan_row(const h2v* zh, float tau,
                                         float& f, float& g, float& c) {
  float ff = 0.f, gg = 0.f, cc = 0.f;
#if HAVE_FDOT2
  _Float16 th = (_Float16)tau;
  h2v t2 = {th, th};
  h2v zero2 = {(_Float16)0.f, (_Float16)0.f};
  h2v one2  = {(_Float16)1.f, (_Float16)1.f};
  h2v big2  = {(_Float16)60000.f, (_Float16)60000.f};
#pragma unroll
  for (int i = 0; i < 16; i++) {
    h2v d = __builtin_elementwise_max(zh[i] - t2, zero2);
    ff = __builtin_amdgcn_fdot2(d, d, ff, false);
    gg = __builtin_amdgcn_fdot2(d, one2, gg, false);
    h2v mm = __builtin_elementwise_min(d * big2, one2);
    cc = __builtin_amdgcn_fdot2(mm, one2, cc, false);
  }
#else
#pragma unroll
  for (int i = 0; i < 16; i++) {
#pragma unroll
    for (int j = 0; j < 2; j++) {
      float z = (float)zh[i][j];
      float d = fmaxf(z - tau, 0.f);
      ff = fmaf(d, d, ff);
      gg += d;
      cc += (d > 0.f) ? 1.f : 0.f;
    }
  }
#endif
  f = ff; g = gg; c = cc;
}

// safeguarded step: exact-quadratic from left (f>=1), Newton-back if overshot
__device__ __forceinline__ float nstep(float tau, float f, float g, float c, float m) {
  float num  = f - 1.0f;
  float disc = fmaxf(g*g - c*num, 0.f);
  float den  = (num >= 0.f) ? (g + sqrtf(disc)) : (2.0f * g);
  float t = tau + num / fmaxf(den, 1e-12f);
  return fminf(t, m - 0.01f);    // tau* <= m - 1/sqrt(2048) = m-0.022; keeps c>=1
}

// ---------------------------------------------------------------- MFMA attention
// Block = 16 q-rows of one (b,h); 512 threads = 8 waves; wave w owns k-cols
// [w*256, w*256+256) for QK^T and PV. z staged fp16 in LDS; Newton is
// wave-private (wave w owns rows 2w, 2w+1 fully in registers).
__global__ __launch_bounds__(512, 4) void attn_k(const unsigned short* __restrict__ Qb,
    const unsigned short* __restrict__ Kb, const _Float16* __restrict__ VTb,
    float* __restrict__ AO) {
  __shared__ __align__(16) _Float16 zbuf[16 * ZPITCH];   // 65792 B
  __shared__ float taubuf[16];

  int tid = threadIdx.x, lane = tid & 63, w = tid >> 6;
  int g = lane >> 4, li = lane & 15;
  int qbase = blockIdx.x * 16, bh = blockIdx.y;
  const unsigned short* Qh  = Qb  + (size_t)bh * NSEQ * DK;
  const unsigned short* Kh  = Kb  + (size_t)bh * NSEQ * DK;
  const _Float16*       VTh = VTb + (size_t)bh * DK * NSEQ;
  int kc = w * 256;
  const float zs = 0.044194173824159216f;   // 0.5 / sqrt(128)

  // ---- Q A-frags
  bf16x8 aq[4];
  {
    const unsigned short* qp = Qh + (size_t)(qbase + li) * DK + g * 8;
#pragma unroll
    for (int db = 0; db < 4; db++) aq[db] = *(const bf16x8*)(qp + db * 32);
  }

  // ---- P1: QK^T via MFMA; zacc[t] covers cols kc+t*16..+15, rows g*4+r
  f32x4 zacc[16];
#pragma unroll
  for (int t = 0; t < 16; t++) zacc[t] = (f32x4){0.f, 0.f, 0.f, 0.f};
  for (int t = 0; t < 16; t++) {
    const unsigned short* kp = Kh + (size_t)(kc + t*16 + li) * DK + g * 8;
#pragma unroll
    for (int db = 0; db < 4; db++) {
      bf16x8 bk = *(const bf16x8*)(kp + db * 32);
      zacc[t] = __builtin_amdgcn_mfma_f32_16x16x32_bf16(aq[db], bk, zacc[t], 0, 0, 0);
    }
  }
  // ---- P1b: z -> fp16 LDS
#pragma unroll
  for (int t = 0; t < 16; t++) {
#pragma unroll
    for (int r = 0; r < 4; r++)
      zbuf[(size_t)(g*4 + r) * ZPITCH + kc + t*16 + li] = (_Float16)(zacc[t][r] * zs);
  }
  __syncthreads();                                      // B1: z complete

  // ---- P2: wave-private Newton on rows 2w, 2w+1 (full 2048 cols in regs)
  int rA = 2*w, rB = 2*w + 1;
  union { h8 v[4]; h2v h[16]; } ua, ub;
#pragma unroll
  for (int i = 0; i < 4; i++) {
    ua.v[i] = *(const h8*)(zbuf + (size_t)rA * ZPITCH + i*512 + lane*8);
    ub.v[i] = *(const h8*)(zbuf + (size_t)rB * ZPITCH + i*512 + lane*8);
  }
  // row maxes
  h2v mxa = ua.h[0], mxb = ub.h[0];
#pragma unroll
  for (int i = 1; i < 16; i++) {
    mxa = __builtin_elementwise_max(mxa, ua.h[i]);
    mxb = __builtin_elementwise_max(mxb, ub.h[i]);
  }
  float mA = fmaxf((float)mxa[0], (float)mxa[1]);
  float mB = fmaxf((float)mxb[0], (float)mxb[1]);
#pragma unroll
  for (int off = 32; off > 0; off >>= 1) {
    mA = fmaxf(mA, __shfl_xor(mA, off));
    mB = fmaxf(mB, __shfl_xor(mB, off));
  }
  float tauA = mA - 1.0f, tauB = mB - 1.0f;
  for (int it = 0; it < NEWTON_IT; ++it) {
    float fA, gA, cA, fB, gB, cB;
    scan_row(ua.h, tauA, fA, gA, cA);
    scan_row(ub.h, tauB, fB, gB, cB);
#pragma unroll
    for (int off = 32; off > 0; off >>= 1) {
      fA += __shfl_xor(fA, off); gA += __shfl_xor(gA, off); cA += __shfl_xor(cA, off);
      fB += __shfl_xor(fB, off); gB += __shfl_xor(gB, off); cB += __shfl_xor(cB, off);
    }
    tauA = nstep(tauA, fA, gA, cA, mA);
    tauB = nstep(tauB, fB, gB, cB, mB);
  }
  if (lane == 0) { taubuf[rA] = tauA; taubuf[rB] = tauB; }
  __syncthreads();                                      // B2: taus ready

  // ---- P3: PV A-frags on the fly: p = relu(z - tau[row])^2, rows=li
  h8 ap[8];
  {
    float tli = taubuf[li];
    _Float16 th = (_Float16)tli;
    h2v t2 = {th, th};
    h2v zero2 = {(_Float16)0.f, (_Float16)0.f};
#pragma unroll
    for (int kk = 0; kk < 8; kk++) {
      union { h8 v; h2v h[4]; } u;
      u.v = *(const h8*)(zbuf + (size_t)li * ZPITCH + kc + kk*32 + g*8);
#pragma unroll
      for (int j = 0; j < 4; j++) {
        h2v d = __builtin_elementwise_max(u.h[j] - t2, zero2);
        u.h[j] = d * d;
      }
      ap[kk] = u.v;
    }
  }
  __syncthreads();                                      // B3: zbuf free for reuse

  // ---- P4: PV via MFMA f16 over this wave's k-chunk; B = V^T (global, fp16)
  f32x4 oacc[8];
#pragma unroll
  for (int dt = 0; dt < 8; dt++) oacc[dt] = (f32x4){0.f, 0.f, 0.f, 0.f};
#pragma unroll
  for (int dt = 0; dt < 8; dt++) {
    const _Float16* vp = VTh + (size_t)(dt*16 + li) * NSEQ + kc + g * 8;
#pragma unroll
    for (int kk = 0; kk < 8; kk++) {
      h8 bv = *(const h8*)(vp + kk * 32);
      oacc[dt] = __builtin_amdgcn_mfma_f32_16x16x32_f16(ap[kk], bv, oacc[dt], 0, 0, 0);
    }
  }

  // ---- cross-wave O reduction (reuse zbuf as f32 partial buffer)
  float* obuf = (float*)zbuf;                           // 8*16*128*4 = 64 KiB <= 65792
#pragma unroll
  for (int dt = 0; dt < 8; dt++)
#pragma unroll
    for (int r = 0; r < 4; r++)
      obuf[(size_t)w*2048 + (g*4 + r)*128 + dt*16 + li] = oacc[dt][r];
  __syncthreads();                                      // B4

  int q = tid >> 5, d4 = (tid & 31) * 4;
  float4 s = make_float4(0.f, 0.f, 0.f, 0.f);
#pragma unroll
  for (int ww = 0; ww < 8; ww++) {
    const float* ob = obuf + (size_t)ww*2048 + q*128 + d4;
    s.x += ob[0]; s.y += ob[1]; s.z += ob[2]; s.w += ob[3];
  }
  int b = bh / NH, h = bh % NH;
  *(float4*)&AO[((size_t)b*NSEQ + qbase + q)*DM + h*DK + d4] = s;
}

// ---------------------------------------------------------------- LN + residual
__global__ __launch_bounds__(256) void ln_k(const float* __restrict__ AO,
    const float* __restrict__ xT, const float* __restrict__ ga,
    const float* __restrict__ gb, float* __restrict__ outp) {
  int lane = threadIdx.x & 63;
  int wave = threadIdx.x >> 6;
  int row  = blockIdx.x * 4 + wave;
  const float* ao = AO + (size_t)row*DM;
  float2 c0 = *(const float2*)(ao + lane*2);
  float2 c1 = *(const float2*)(ao + 128 + lane*2);
  float2 c2 = *(const float2*)(ao + 256 + lane*2);
  float s  = c0.x + c0.y + c1.x + c1.y + c2.x + c2.y;
  float ss = c0.x*c0.x + c0.y*c0.y + c1.x*c1.x + c1.y*c1.y + c2.x*c2.x + c2.y*c2.y;
#pragma unroll
  for (int off = 32; off > 0; off >>= 1) {
    s  += __shfl_xor(s,  off);
    ss += __shfl_xor(ss, off);
  }
  float mean = s * (1.0f / 384.0f);
  float var  = (ss - 384.0f*mean*mean) * (1.0f / 383.0f);   // Bessel (n-1)
  var = fmaxf(var, 0.f);
  float inv = 1.0f / (sqrtf(var) + 1e-6f);                  // eps added to STD
  const float* xr = xT + (size_t)row*DM;
  float* op = outp + (size_t)row*DM;
#pragma unroll
  for (int ch = 0; ch < 3; ch++) {
    int i0 = ch*128 + lane*2;
    float2 g  = *(const float2*)(ga + i0);
    float2 bb = *(const float2*)(gb + i0);
    float2 xv = *(const float2*)(xr + i0);
    float2 av = (ch == 0) ? c0 : (ch == 1) ? c1 : c2;
    float2 o;
    o.x = g.x*(av.x - mean)*inv + bb.x + xv.x;
    o.y = g.y*(av.y - mean)*inv + bb.y + xv.y;
    *(float2*)(op + i0) = o;
  }
}

// ---------------------------------------------------------------- launch
extern "C" void kernel_launch(void* const* d_in, const int* in_sizes, int n_in,
                              void* d_out, int out_size, void* d_ws, size_t ws_size,
                              hipStream_t stream) {
  const float* x  = (const float*)d_in[0];
  const float* wq = (const float*)d_in[1];
  const float* bq = (const float*)d_in[2];
  const float* wk = (const float*)d_in[3];
  const float* bk = (const float*)d_in[4];
  const float* wv = (const float*)d_in[5];
  const float* bv = (const float*)d_in[6];
  const float* la = (const float*)d_in[7];
  const float* lb = (const float*)d_in[8];
  float* out = (float*)d_out;

  // ws: xT f32 | AO f32 | Qb bf16 | Kb bf16 | VT f16 | xbf bf16 | wbf bf16
  char* wsb = (char*)d_ws;
  float* xT = (float*)wsb;
  float* AO = (float*)(wsb + (size_t)SEG*4);
  unsigned short* Qb  = (unsigned short*)(wsb + (size_t)SEG*8);
  unsigned short* Kb  = (unsigned short*)(wsb + (size_t)SEG*8 + (size_t)SEG*2);
  unsigned short* VT  = (unsigned short*)(wsb + (size_t)SEG*8 + (size_t)SEG*4);
  unsigned short* xbf = (unsigned short*)(wsb + (size_t)SEG*8 + (size_t)SEG*6);
  unsigned short* wbf = (unsigned short*)(wsb + (size_t)SEG*8 + (size_t)SEG*8);

  hipLaunchKernelGGL(transpose_k, dim3(NSEQ/32, DM/32, BATCH), dim3(256), 0, stream,
                     x, xT, xbf);
  hipLaunchKernelGGL(wconv_k, dim3(DM*DM/1024, 3), dim3(256), 0, stream, wq, wk, wv, wbf);
  hipLaunchKernelGGL(proj_mfma_k, dim3(NTOK/128, NH, 3), dim3(256), 0, stream,
                     xbf, wbf, bq, bk, bv, Qb, Kb, VT);
  hipLaunchKernelGGL(attn_k, dim3(NSEQ/16, BATCH*NH), dim3(512), 0, stream,
                     Qb, Kb, (const _Float16*)VT, AO);
  hipLaunchKernelGGL(ln_k, dim3(BATCH*NSEQ/4), dim3(256), 0, stream, AO, xT, la, lb, out);
}